// Round 2
// baseline (4377.405 us; speedup 1.0000x reference)
//
#include <hip/hip_runtime.h>
#include <math.h>

// Problem constants
#define BB   64
#define HENC 512
#define EE   512
#define HH   1024
#define VV   32000
#define TT   64
#define G3   3072   // 3*H
#define SOS_TOK 1
#define EOS_TOK 2
#define KSEG 128
#define NP2  4000   // argmax partial entries (2000 n-tiles * top-2)
#define GHB  192    // gh blocks fused into k_logits
#define LOGB 250    // logits blocks (4 waves x 2 n-tiles each)

typedef __attribute__((ext_vector_type(8))) short short8;
typedef __attribute__((ext_vector_type(8))) unsigned short ushort8;
typedef __attribute__((ext_vector_type(4))) float f32x4;
typedef unsigned short ushort;
typedef unsigned int uint;

// Workspace layout (float offsets).
#define OFF_FLATT 0u          // 65536
#define OFF_XT    65536u      // 32768
#define OFF_HT    98304u      // 65536   hT[g][b] (g-major, for gh GEMM A-reads)
#define OFF_GC    163840u     // 196608  gc[b][n] = b_ih + context@Wih_ctx
#define OFF_P     360448u     // 8*64*3072 = 1572864 gate partials
#define OFF_PH    1933312u    // 8*65536 = 524288  h0 partials
#define OFF_PMAX  2457600u    // 256000  pmax[b][p]  (b-major, contiguous per batch)
#define OFF_PIDX  2713600u    // 256000
#define OFF_FIN   2969600u    // 128 (double-buffered by t parity)
#define OFF_HA    2969728u    // 32768 floats (64x1024 bf16 A-frag packed h)
#define OFF_HB    3002496u    // 65536 floats  hB[b][k] (b-major fp32 h for rescore)
#define OFF_WB    3068032u    // 16384000 floats (32000x1024 bf16 B-frag W) [optional]
#define OFF_END   19452032u
#define NEED_BYTES ((size_t)OFF_END * 4u)   // 77,808,128

#define NEG_INF (-3.402823466e38f)
#define IDX_INF 0x7fffffff

__device__ __forceinline__ ushort f2bf(float x) {
  uint u = __float_as_uint(x);
  u = u + 0x7fffu + ((u >> 16) & 1u);   // RNE
  return (ushort)(u >> 16);
}

// Strict total order: larger value wins; ties -> smaller index wins.
#define BETTER(av, ai, bv, bi) ((av) > (bv) || ((av) == (bv) && (ai) < (bi)))

// ---------------------------------------------------------------------------
__global__ __launch_bounds__(256) void k_setup(const float* __restrict__ enc,
                                               const float* __restrict__ emb,
                                               float* __restrict__ flatT,
                                               float* __restrict__ xT,
                                               int* __restrict__ fin0) {
  int idx = blockIdx.x * 256 + threadIdx.x;   // 65536
  int j = idx >> 6, b = idx & 63;
  float v = (j < 512) ? enc[b * 512 + j] : enc[32768 + b * 512 + (j - 512)];
  flatT[j * 64 + b] = v;
  if (j < 512) xT[j * 64 + b] = emb[SOS_TOK * EE + j];
  if (idx < 64) fin0[idx] = 0;
}

// ---------------------------------------------------------------------------
// Optional: pack out_w fp32 -> bf16 in B-fragment stream order.
// chunk c = (nt*32 + kc)*64 + lane ; element j: n = nt*16+(lane&15), k = kc*32+(lane>>4)*8+j
__global__ __launch_bounds__(256) void k_packWb(const float* __restrict__ W,
                                                ushort* __restrict__ Wb) {
  int t = blockIdx.x * 256 + threadIdx.x;     // 4,096,000 chunks
  int l = t & 63, kc = (t >> 6) & 31, nt = t >> 11;
  int n = nt * 16 + (l & 15);
  int k = kc * 32 + ((l >> 4) << 3);
  const float* src = W + (size_t)n * 1024 + k;
  ushort8 r;
  #pragma unroll
  for (int j = 0; j < 8; ++j) r[j] = f2bf(src[j]);
  *(ushort8*)(Wb + (size_t)t * 8) = r;
}

// ---------------------------------------------------------------------------
// Generic fp32 skinny GEMM partial (setup only).
__global__ __launch_bounds__(256) void k_gemm(const float* __restrict__ AT,
                                              const float* __restrict__ W,
                                              int ldw, int wofs,
                                              float* __restrict__ C, int N) {
  __shared__ float Ws[KSEG][65];
  int tid = threadIdx.x;
  int n0 = blockIdx.x * 64;
  int k0 = blockIdx.y * KSEG;

  #pragma unroll
  for (int r = 0; r < 8; ++r) {
    int f4 = tid + 256 * r;
    int n = f4 >> 5, kq = f4 & 31;
    float4 w4 = *(const float4*)&W[(size_t)(n0 + n) * ldw + wofs + k0 + 4 * kq];
    Ws[4 * kq + 0][n] = w4.x;
    Ws[4 * kq + 1][n] = w4.y;
    Ws[4 * kq + 2][n] = w4.z;
    Ws[4 * kq + 3][n] = w4.w;
  }
  __syncthreads();

  int wv = __builtin_amdgcn_readfirstlane(tid >> 6);
  int lane = tid & 63;
  int mb = wv * 16;

  float acc[16];
  #pragma unroll
  for (int i = 0; i < 16; ++i) acc[i] = 0.f;

  #pragma unroll 4
  for (int kk = 0; kk < KSEG; ++kk) {
    float w = Ws[kk][lane];
    const float* a = &AT[(size_t)(k0 + kk) * 64 + mb];
    float av[16];
    *(float4*)&av[0]  = *(const float4*)(a + 0);
    *(float4*)&av[4]  = *(const float4*)(a + 4);
    *(float4*)&av[8]  = *(const float4*)(a + 8);
    *(float4*)&av[12] = *(const float4*)(a + 12);
    #pragma unroll
    for (int i = 0; i < 16; ++i) acc[i] += av[i] * w;
  }

  float* dst = C + ((size_t)blockIdx.y * 64 + mb) * N + n0 + lane;
  #pragma unroll
  for (int i = 0; i < 16; ++i) dst[(size_t)i * N] = acc[i];
}

// ---------------------------------------------------------------------------
// Per-step gates GEMM with base_by selector.
// by_eff < 4  -> gi seg (xT @ W_ih[:, :512]), K-seg 128 each, P slot = by_eff
// by_eff >= 4 -> gh (hT @ W_hh), 256 K each (two 128 stages), P slot = by_eff
__global__ __launch_bounds__(256) void k_gates(const float* __restrict__ xT,
                                               const float* __restrict__ hT,
                                               const float* __restrict__ Wih,
                                               const float* __restrict__ Whh,
                                               float* __restrict__ P,
                                               int base_by) {
  __shared__ float Ws[KSEG][65];
  int tid = threadIdx.x;
  int n0 = blockIdx.x * 64;
  int by = blockIdx.y + base_by;
  bool gi = (by < 4);
  const float* AT = gi ? xT : hT;
  const float* W  = gi ? Wih : Whh;
  int ldw = gi ? 1536 : 1024;
  int nsegs = gi ? 1 : 2;
  int k0base = gi ? by * KSEG : (by - 4) * 256;

  int wv = __builtin_amdgcn_readfirstlane(tid >> 6);
  int lane = tid & 63;
  int mb = wv * 16;

  float acc[16];
  #pragma unroll
  for (int i = 0; i < 16; ++i) acc[i] = 0.f;

  for (int s = 0; s < nsegs; ++s) {
    int k0 = k0base + s * KSEG;
    if (s) __syncthreads();
    #pragma unroll
    for (int r = 0; r < 8; ++r) {
      int f4 = tid + 256 * r;
      int n = f4 >> 5, kq = f4 & 31;
      float4 w4 = *(const float4*)&W[(size_t)(n0 + n) * ldw + k0 + 4 * kq];
      Ws[4 * kq + 0][n] = w4.x;
      Ws[4 * kq + 1][n] = w4.y;
      Ws[4 * kq + 2][n] = w4.z;
      Ws[4 * kq + 3][n] = w4.w;
    }
    __syncthreads();
    #pragma unroll 4
    for (int kk = 0; kk < KSEG; ++kk) {
      float w = Ws[kk][lane];
      const float* a = &AT[(size_t)(k0 + kk) * 64 + mb];
      float av[16];
      *(float4*)&av[0]  = *(const float4*)(a + 0);
      *(float4*)&av[4]  = *(const float4*)(a + 4);
      *(float4*)&av[8]  = *(const float4*)(a + 8);
      *(float4*)&av[12] = *(const float4*)(a + 12);
      #pragma unroll
      for (int i = 0; i < 16; ++i) acc[i] += av[i] * w;
    }
  }

  float* dst = P + ((size_t)by * 64 + mb) * G3 + n0 + lane;
  #pragma unroll
  for (int i = 0; i < 16; ++i) dst[(size_t)i * G3] = acc[i];
}

// ---------------------------------------------------------------------------
__global__ __launch_bounds__(256) void k_reduce_gc(const float* __restrict__ P,
                                                   const float* __restrict__ b_ih,
                                                   float* __restrict__ gc) {
  int idx = blockIdx.x * 256 + threadIdx.x;  // 196608
  int n = idx % G3;
  float s = b_ih[n];
  #pragma unroll
  for (int p = 0; p < 8; ++p) s += P[(size_t)p * (64 * G3) + idx];
  gc[idx] = s;
}

// Pack one h element (m=b, k=g) into bf16 A-frag layout.
__device__ __forceinline__ void packH1(float v, int b, int g, ushort* hA) {
  int kc = g >> 5, q = (g >> 3) & 3, j = g & 7;
  int lane = (q << 4) | (b & 15), mt = b >> 4;
  size_t fi = ((size_t)((mt * 32 + kc) * 64 + lane)) * 8 + j;
  hA[fi] = f2bf(v);
}

__global__ __launch_bounds__(256) void k_reduce_h0(const float* __restrict__ Ph,
                                                   const float* __restrict__ Wh_b,
                                                   float* __restrict__ hT,
                                                   float* __restrict__ hB,
                                                   ushort* __restrict__ hA) {
  int idx = blockIdx.x * 256 + threadIdx.x;  // 65536
  int b = idx >> 10, g = idx & 1023;
  float s = Wh_b[g];
  #pragma unroll
  for (int p = 0; p < 8; ++p) s += Ph[(size_t)p * 65536 + idx];
  hT[g * 64 + b] = s;
  hB[idx] = s;                 // hB[b][g]
  packH1(s, b, g, hA);
}

// ---------------------------------------------------------------------------
// GRU combine; emits fp32 hT (g-major), hB (b-major) and bf16 A-frag hA.
// P slots 0..3 gi, 4..7 gh. 256 blocks: b = bx>>2, g-range (bx&3)*256+tid.
__global__ __launch_bounds__(256) void k_combine(const float* __restrict__ P,
                                                 const float* __restrict__ gc,
                                                 const float* __restrict__ b_hh,
                                                 float* __restrict__ hT,
                                                 float* __restrict__ hB,
                                                 ushort* __restrict__ hA) {
  int b = blockIdx.x >> 2;
  int g = ((blockIdx.x & 3) << 8) + threadIdx.x;
  float ir = gc[b * G3 + g];
  float iz = gc[b * G3 + 1024 + g];
  float in_ = gc[b * G3 + 2048 + g];
  float hr = b_hh[g], hz = b_hh[1024 + g], hn = b_hh[2048 + g];
  #pragma unroll
  for (int p = 0; p < 4; ++p) {
    const float* row = P + ((size_t)p * 64 + b) * G3;
    ir += row[g]; iz += row[1024 + g]; in_ += row[2048 + g];
  }
  #pragma unroll
  for (int p = 4; p < 8; ++p) {
    const float* row = P + ((size_t)p * 64 + b) * G3;
    hr += row[g]; hz += row[1024 + g]; hn += row[2048 + g];
  }
  float rr = 1.f / (1.f + expf(-(ir + hr)));
  float zz = 1.f / (1.f + expf(-(iz + hz)));
  float nn = tanhf(in_ + rr * hn);
  float hold = hT[g * 64 + b];
  float hnew = (1.f - zz) * nn + zz * hold;
  hT[g * 64 + b] = hnew;
  hB[b * 1024 + g] = hnew;
  packH1(hnew, b, g, hA);
}

// ---------------------------------------------------------------------------
__device__ __forceinline__ short8 cvt8(const float* p) {
  float4 x = *(const float4*)p;
  float4 y = *(const float4*)(p + 4);
  short8 r;
  r[0] = (short)f2bf(x.x); r[1] = (short)f2bf(x.y);
  r[2] = (short)f2bf(x.z); r[3] = (short)f2bf(x.w);
  r[4] = (short)f2bf(y.x); r[5] = (short)f2bf(y.y);
  r[6] = (short)f2bf(y.z); r[7] = (short)f2bf(y.w);
  return r;
}

// Per-n-tile epilogue: bias + per-row top-2 over the wave's 16 columns,
// written b-major: pmax[b*NP2 + nt*2 + {0,1}].
__device__ __forceinline__ void top2_epilogue(const f32x4* acc, int nt, int nl, int q,
                                              const float* __restrict__ bo,
                                              float* __restrict__ pmax,
                                              int* __restrict__ pidx) {
  float bias = bo[nt * 16 + nl];
  int myn = nt * 16 + nl;
  #pragma unroll
  for (int mt = 0; mt < 4; ++mt) {
    #pragma unroll
    for (int r = 0; r < 4; ++r) {
      float v1 = acc[mt][r] + bias; int i1 = myn;
      float v2 = NEG_INF;           int i2 = IDX_INF;
      #pragma unroll
      for (int s = 1; s < 16; s <<= 1) {
        float ov1 = __shfl_xor(v1, s, 64); int oi1 = __shfl_xor(i1, s, 64);
        float ov2 = __shfl_xor(v2, s, 64); int oi2 = __shfl_xor(i2, s, 64);
        bool take = BETTER(ov1, oi1, v1, i1);
        float n1v = take ? ov1 : v1; int n1i = take ? oi1 : i1;
        float cav = take ? v1 : ov1; int cai = take ? i1 : oi1;
        float cbv = take ? ov2 : v2; int cbi = take ? oi2 : i2;
        bool bb = BETTER(cbv, cbi, cav, cai);
        v1 = n1v; i1 = n1i;
        v2 = bb ? cbv : cav; i2 = bb ? cbi : cai;
      }
      if (nl == 0) {
        int m = mt * 16 + q * 4 + r;
        pmax[(size_t)m * NP2 + nt * 2 + 0] = v1;
        pidx[(size_t)m * NP2 + nt * 2 + 0] = i1;
        pmax[(size_t)m * NP2 + nt * 2 + 1] = v2;
        pidx[(size_t)m * NP2 + nt * 2 + 1] = i2;
      }
    }
  }
}

// MFMA logits + fused next-step gh gates.
// Blocks 0..GHB-1: gh GEMM for step t+1 (hT(t+1) @ W_hh -> P slots 4..7).
// Blocks GHB..GHB+LOGB-1: logits; wave = 2 n-tiles (32 vocab) x 4 m-tiles,
// depth-4 ring; the A-frag stream (128 reads) is shared across both n-tiles,
// halving per-step hA L2 traffic vs 1 n-tile/wave.
template <bool PACKED>
__global__ __launch_bounds__(256) void k_logits(const ushort* __restrict__ Wb,
                                                const float* __restrict__ Wf,
                                                const ushort* __restrict__ hA,
                                                const float* __restrict__ bo,
                                                float* __restrict__ pmax,
                                                int* __restrict__ pidx,
                                                const float* __restrict__ hT,
                                                const float* __restrict__ Whh,
                                                float* __restrict__ P) {
  __shared__ float Ws[KSEG][65];
  int tid = threadIdx.x, wv = tid >> 6, lane = tid & 63;

  if (blockIdx.x < GHB) {
    // ---- gh path: hT @ W_hh^T into P slots 4..7 (for NEXT step's combine) ----
    int bx = blockIdx.x;
    int by = bx / 48;               // 0..3
    int n0 = (bx % 48) * 64;
    int slot = 4 + by;
    int k0base = by * 256;

    int wvs = __builtin_amdgcn_readfirstlane(wv);
    int mb = wvs * 16;

    float acc[16];
    #pragma unroll
    for (int i = 0; i < 16; ++i) acc[i] = 0.f;

    for (int s = 0; s < 2; ++s) {
      int k0 = k0base + s * KSEG;
      if (s) __syncthreads();
      #pragma unroll
      for (int r = 0; r < 8; ++r) {
        int f4 = tid + 256 * r;
        int n = f4 >> 5, kq = f4 & 31;
        float4 w4 = *(const float4*)&Whh[(size_t)(n0 + n) * 1024 + k0 + 4 * kq];
        Ws[4 * kq + 0][n] = w4.x;
        Ws[4 * kq + 1][n] = w4.y;
        Ws[4 * kq + 2][n] = w4.z;
        Ws[4 * kq + 3][n] = w4.w;
      }
      __syncthreads();
      #pragma unroll 4
      for (int kk = 0; kk < KSEG; ++kk) {
        float w = Ws[kk][lane];
        const float* a = &hT[(size_t)(k0 + kk) * 64 + mb];
        float av[16];
        *(float4*)&av[0]  = *(const float4*)(a + 0);
        *(float4*)&av[4]  = *(const float4*)(a + 4);
        *(float4*)&av[8]  = *(const float4*)(a + 8);
        *(float4*)&av[12] = *(const float4*)(a + 12);
        #pragma unroll
        for (int i = 0; i < 16; ++i) acc[i] += av[i] * w;
      }
    }

    float* dst = P + ((size_t)slot * 64 + mb) * G3 + n0 + lane;
    #pragma unroll
    for (int i = 0; i < 16; ++i) dst[(size_t)i * G3] = acc[i];
    return;
  }

  // ---- logits path: 2 n-tiles per wave ----
  int nt0 = (((blockIdx.x - GHB) * 4 + wv) << 1);   // 0,2,..,1998
  int nl = lane & 15, q = lane >> 4;

  const short8* Bp0 = (const short8*)Wb + ((size_t)nt0 * 2048 + lane);
  const short8* Bp1 = Bp0 + 2048;
  const float*  Bf0 = Wf + (size_t)(nt0 * 16 + nl) * 1024 + (q << 3);
  const float*  Bf1 = Bf0 + 16 * 1024;
  const short8* Ap = (const short8*)hA + lane;

  f32x4 acc0[4], acc1[4];
  #pragma unroll
  for (int m = 0; m < 4; ++m) {
    acc0[m] = (f32x4){0.f, 0.f, 0.f, 0.f};
    acc1[m] = (f32x4){0.f, 0.f, 0.f, 0.f};
  }

  short8 b0R[4], b1R[4], aR[4][4];
  #pragma unroll
  for (int d = 0; d < 4; ++d) {
    b0R[d] = PACKED ? Bp0[d * 64] : cvt8(Bf0 + d * 32);
    b1R[d] = PACKED ? Bp1[d * 64] : cvt8(Bf1 + d * 32);
    #pragma unroll
    for (int m = 0; m < 4; ++m) aR[d][m] = Ap[(m * 32 + d) * 64];
  }

  #pragma unroll
  for (int kc = 0; kc < 32; ++kc) {
    const int sl = kc & 3;
    #pragma unroll
    for (int m = 0; m < 4; ++m)
      acc0[m] = __builtin_amdgcn_mfma_f32_16x16x32_bf16(aR[sl][m], b0R[sl], acc0[m], 0, 0, 0);
    #pragma unroll
    for (int m = 0; m < 4; ++m)
      acc1[m] = __builtin_amdgcn_mfma_f32_16x16x32_bf16(aR[sl][m], b1R[sl], acc1[m], 0, 0, 0);
    if (kc < 28) {
      b0R[sl] = PACKED ? Bp0[(kc + 4) * 64] : cvt8(Bf0 + (kc + 4) * 32);
      b1R[sl] = PACKED ? Bp1[(kc + 4) * 64] : cvt8(Bf1 + (kc + 4) * 32);
      #pragma unroll
      for (int m = 0; m < 4; ++m) aR[sl][m] = Ap[(m * 32 + kc + 4) * 64];
    }
  }

  top2_epilogue(acc0, nt0 + 0, nl, q, bo, pmax, pidx);
  top2_epilogue(acc1, nt0 + 1, nl, q, bo, pmax, pidx);
}

// ---------------------------------------------------------------------------
// Per-batch finisher: low-barrier top-4 selection -> fp64 rescore -> token,
// fin, embedding gather. One block per batch.
// Selection: per-thread sorted top-4 (16 contiguous candidates, all indices
// distinct within a batch) -> 6-level shfl_xor bitonic merge (no barriers)
// -> one LDS merge of 4 wave results (1 barrier).
__global__ __launch_bounds__(256) void k_finish(const float* __restrict__ pmax,
                                                const int* __restrict__ pidx,
                                                const float* __restrict__ hB,
                                                const float* __restrict__ Wf,
                                                const float* __restrict__ bo,
                                                const float* __restrict__ emb,
                                                const int* __restrict__ fin_old,
                                                int* __restrict__ fin_new,
                                                float* __restrict__ xT,
                                                float* __restrict__ tok_out, int t) {
  __shared__ float  sv[16];
  __shared__ int    si[16];
  __shared__ int    sch[4];
  __shared__ double ssc[4];
  __shared__ int    sinp;
  int b = blockIdx.x, tid = threadIdx.x;
  int wv = tid >> 6, ln = tid & 63;

  float v0 = NEG_INF, v1 = NEG_INF, v2 = NEG_INF, v3 = NEG_INF;
  int   i0 = IDX_INF, i1 = IDX_INF, i2 = IDX_INF, i3 = IDX_INF;

  // Insert (cv,ci) into the descending sorted top-4 (v0..v3).
  #define INS4(cv, ci)                                                   \
    {                                                                    \
      bool c0 = BETTER(cv, ci, v0, i0);                                  \
      bool c1 = BETTER(cv, ci, v1, i1);                                  \
      bool c2 = BETTER(cv, ci, v2, i2);                                  \
      bool c3 = BETTER(cv, ci, v3, i3);                                  \
      v3 = c3 ? (c2 ? v2 : (cv)) : v3;  i3 = c3 ? (c2 ? i2 : (ci)) : i3; \
      v2 = c2 ? (c1 ? v1 : (cv)) : v2;  i2 = c2 ? (c1 ? i1 : (ci)) : i2; \
      v1 = c1 ? (c0 ? v0 : (cv)) : v1;  i1 = c1 ? (c0 ? i0 : (ci)) : i1; \
      v0 = c0 ? (cv) : v0;              i0 = c0 ? (ci) : i0;             \
    }

  if (tid < 250) {                       // 250*16 == NP2
    const float* pm = pmax + (size_t)b * NP2 + tid * 16;
    const int*   pi = pidx + (size_t)b * NP2 + tid * 16;
    #pragma unroll
    for (int j4 = 0; j4 < 4; ++j4) {
      float4 c4 = *(const float4*)(pm + j4 * 4);
      int4   x4 = *(const int4*)(pi + j4 * 4);
      INS4(c4.x, x4.x);
      INS4(c4.y, x4.y);
      INS4(c4.z, x4.z);
      INS4(c4.w, x4.w);
    }
  }

  // Compare-exchange keeping the better at (xv,xi).
  #define CESW(xv, xi, yv, yi)                                     \
    {                                                              \
      bool sw_ = BETTER(yv, yi, xv, xi);                           \
      float tv_ = xv; int ti_ = xi;                                \
      xv = sw_ ? yv : xv;  xi = sw_ ? yi : xi;                     \
      yv = sw_ ? tv_ : yv; yi = sw_ ? ti_ : yi;                    \
    }

  // Wave-level butterfly merge of sorted top-4 lists (no barriers).
  for (int s = 1; s < 64; s <<= 1) {
    float w0 = __shfl_xor(v0, s, 64), w1 = __shfl_xor(v1, s, 64);
    float w2 = __shfl_xor(v2, s, 64), w3 = __shfl_xor(v3, s, 64);
    int   j0 = __shfl_xor(i0, s, 64), j1 = __shfl_xor(i1, s, 64);
    int   j2 = __shfl_xor(i2, s, 64), j3 = __shfl_xor(i3, s, 64);
    // bitonic 8-seq: [v0 v1 v2 v3 w3 w2 w1 w0]; half-clean keeps max in v.
    if (BETTER(w3, j3, v0, i0)) { v0 = w3; i0 = j3; }
    if (BETTER(w2, j2, v1, i1)) { v1 = w2; i1 = j2; }
    if (BETTER(w1, j1, v2, i2)) { v2 = w1; i2 = j1; }
    if (BETTER(w0, j0, v3, i3)) { v3 = w0; i3 = j0; }
    // sort the remaining bitonic 4 descending.
    CESW(v0, i0, v2, i2);
    CESW(v1, i1, v3, i3);
    CESW(v0, i0, v1, i1);
    CESW(v2, i2, v3, i3);
  }

  if (ln == 0) {
    sv[wv * 4 + 0] = v0; si[wv * 4 + 0] = i0;
    sv[wv * 4 + 1] = v1; si[wv * 4 + 1] = i1;
    sv[wv * 4 + 2] = v2; si[wv * 4 + 2] = i2;
    sv[wv * 4 + 3] = v3; si[wv * 4 + 3] = i3;
  }
  __syncthreads();

  if (tid == 0) {
    float t0 = NEG_INF, t1 = NEG_INF, t2 = NEG_INF, t3 = NEG_INF;
    int   x0 = IDX_INF, x1 = IDX_INF, x2 = IDX_INF, x3 = IDX_INF;
    #pragma unroll
    for (int e = 0; e < 16; ++e) {
      float cv = sv[e]; int ci = si[e];
      bool c0 = BETTER(cv, ci, t0, x0);
      bool c1 = BETTER(cv, ci, t1, x1);
      bool c2 = BETTER(cv, ci, t2, x2);
      bool c3 = BETTER(cv, ci, t3, x3);
      t3 = c3 ? (c2 ? t2 : cv) : t3;  x3 = c3 ? (c2 ? x2 : ci) : x3;
      t2 = c2 ? (c1 ? t1 : cv) : t2;  x2 = c2 ? (c1 ? x1 : ci) : x2;
      t1 = c1 ? (c0 ? t0 : cv) : t1;  x1 = c1 ? (c0 ? x0 : ci) : x1;
      t0 = c0 ? cv : t0;              x0 = c0 ? ci : x0;
    }
    sch[0] = x0; sch[1] = x1; sch[2] = x2; sch[3] = x3;
  }
  __syncthreads();

  // fp64 rescore: wave c handles candidate c; hB/Wf streamed as float4.
  int c = wv;
  int cid = sch[c];
  const float4* hv4 = (const float4*)(hB + (size_t)b * 1024);
  const float4* wv4 = (const float4*)(Wf + (size_t)cid * 1024);
  double s = 0.0;
  #pragma unroll
  for (int j = 0; j < 4; ++j) {
    float4 hx = hv4[j * 64 + ln];
    float4 wx = wv4[j * 64 + ln];
    s += (double)hx.x * (double)wx.x + (double)hx.y * (double)wx.y +
         (double)hx.z * (double)wx.z + (double)hx.w * (double)wx.w;
  }
  #pragma unroll
  for (int sh = 1; sh < 64; sh <<= 1) s += __shfl_xor(s, sh, 64);
  if (ln == 0) ssc[c] = s + (double)bo[cid];
  __syncthreads();

  if (tid == 0) {
    double bs = ssc[0]; int bid = sch[0];
    #pragma unroll
    for (int j = 1; j < 4; ++j)
      if (ssc[j] > bs || (ssc[j] == bs && sch[j] < bid)) { bs = ssc[j]; bid = sch[j]; }
    int tok = bid;
    int f = fin_old[b] | (tok == EOS_TOK ? 1 : 0);
    tok_out[b * TT + t] = (float)tok;
    fin_new[b] = f;
    sinp = f ? EOS_TOK : tok;
  }
  __syncthreads();
  int inp = sinp;
  xT[tid * 64 + b]         = emb[(size_t)inp * EE + tid];
  xT[(tid + 256) * 64 + b] = emb[(size_t)inp * EE + tid + 256];
}

// ---------------------------------------------------------------------------
__global__ __launch_bounds__(256) void k_hout(const float* __restrict__ hB,
                                              float* __restrict__ outH) {
  int idx = blockIdx.x * 256 + threadIdx.x;  // 65536
  outH[idx] = hB[idx];   // hB is already [b][g] = output layout
}

// ---------------------------------------------------------------------------
extern "C" void kernel_launch(void* const* d_in, const int* in_sizes, int n_in,
                              void* d_out, int out_size, void* d_ws, size_t ws_size,
                              hipStream_t stream) {
  const float* enc   = (const float*)d_in[0];
  const float* emb   = (const float*)d_in[1];
  const float* Wh_w  = (const float*)d_in[2];
  const float* Wh_b  = (const float*)d_in[3];
  const float* W_ih  = (const float*)d_in[4];
  const float* W_hh  = (const float*)d_in[5];
  const float* b_ih  = (const float*)d_in[6];
  const float* b_hh  = (const float*)d_in[7];
  const float* out_w = (const float*)d_in[8];
  const float* out_b = (const float*)d_in[9];

  float* ws    = (float*)d_ws;
  float* flatT = ws + OFF_FLATT;
  float* xT    = ws + OFF_XT;
  float* hT    = ws + OFF_HT;
  float* gc    = ws + OFF_GC;
  float* P     = ws + OFF_P;
  float* Ph    = ws + OFF_PH;
  float* pmax  = ws + OFF_PMAX;
  int*   pidx  = (int*)(ws + OFF_PIDX);
  int*   fin   = (int*)(ws + OFF_FIN);
  ushort* hA   = (ushort*)(ws + OFF_HA);
  float* hB    = ws + OFF_HB;
  ushort* Wb   = (ushort*)(ws + OFF_WB);

  float* outTok = (float*)d_out;
  float* outH   = (float*)d_out + BB * TT;

  const bool packed = (ws_size >= NEED_BYTES);

  // Setup
  k_setup<<<256, 256, 0, stream>>>(enc, emb, flatT, xT, fin);
  if (packed) k_packWb<<<16000, 256, 0, stream>>>(out_w, Wb);
  // gc = b_ih + context @ W_ih[:, 512:1536]^T
  k_gemm<<<dim3(48, 8), 256, 0, stream>>>(flatT, W_ih, 1536, 512, P, G3);
  k_reduce_gc<<<768, 256, 0, stream>>>(P, b_ih, gc);
  // h0 = flat @ Wh_w^T + Wh_b
  k_gemm<<<dim3(16, 8), 256, 0, stream>>>(flatT, Wh_w, 1024, 0, Ph, HH);
  k_reduce_h0<<<256, 256, 0, stream>>>(Ph, Wh_b, hT, hB, hA);
  // gh for t=0 (P slots 4..7); later steps get gh fused into k_logits.
  k_gates<<<dim3(48, 4), 256, 0, stream>>>(xT, hT, W_ih, W_hh, P, 4);

  for (int t = 0; t < TT; ++t) {
    // gi only (P slots 0..3); gh for step t was computed by k_logits(t-1)/setup.
    k_gates<<<dim3(48, 4), 256, 0, stream>>>(xT, hT, W_ih, W_hh, P, 0);
    k_combine<<<256, 256, 0, stream>>>(P, gc, b_hh, hT, hB, hA);
    if (packed)
      k_logits<true><<<LOGB + GHB, 256, 0, stream>>>(Wb, out_w, hA, out_b, pmax, pidx,
                                                     hT, W_hh, P);
    else
      k_logits<false><<<LOGB + GHB, 256, 0, stream>>>(Wb, out_w, hA, out_b, pmax, pidx,
                                                      hT, W_hh, P);
    k_finish<<<64, 256, 0, stream>>>(pmax, pidx, hB, out_w, out_b, emb,
                                     fin + (t & 1) * 64, fin + ((t + 1) & 1) * 64,
                                     xT, outTok, t);
  }
  k_hout<<<256, 256, 0, stream>>>(hB, outH);
}

// Round 3
// 3934.155 us; speedup vs baseline: 1.1127x; 1.1127x over previous
//
#include <hip/hip_runtime.h>
#include <math.h>

// Problem constants
#define BB   64
#define HENC 512
#define EE   512
#define HH   1024
#define VV   32000
#define TT   64
#define G3   3072   // 3*H
#define SOS_TOK 1
#define EOS_TOK 2
#define KSEG 128
#define NP2  4000   // argmax partial entries (2000 n-tiles * top-2)
#define GHB  192    // gh blocks fused into k_logits
#define LOGB 500    // logits blocks (4 waves x 1 n-tile each; 2-tile variant hit VGPR cliff)

typedef __attribute__((ext_vector_type(8))) short short8;
typedef __attribute__((ext_vector_type(8))) unsigned short ushort8;
typedef __attribute__((ext_vector_type(4))) float f32x4;
typedef unsigned short ushort;
typedef unsigned int uint;

// Workspace layout (float offsets).
#define OFF_FLATT 0u          // 65536
#define OFF_XT    65536u      // 32768
#define OFF_HT    98304u      // 65536   hT[g][b] (g-major, for gh GEMM A-reads)
#define OFF_GC    163840u     // 196608  gc[b][n] = b_ih + context@Wih_ctx
#define OFF_P     360448u     // 8*64*3072 = 1572864 gate partials
#define OFF_PH    1933312u    // 8*65536 = 524288  h0 partials
#define OFF_PMAX  2457600u    // 256000  pmax[b][p]  (b-major, contiguous per batch)
#define OFF_PIDX  2713600u    // 256000
#define OFF_FIN   2969600u    // 128 (double-buffered by t parity)
#define OFF_HA    2969728u    // 32768 floats (64x1024 bf16 A-frag packed h)
#define OFF_HB    3002496u    // 65536 floats  hB[b][k] (b-major fp32 h for rescore)
#define OFF_WB    3068032u    // 16384000 floats (32000x1024 bf16 B-frag W) [optional]
#define OFF_END   19452032u
#define NEED_BYTES ((size_t)OFF_END * 4u)   // 77,808,128

#define NEG_INF (-3.402823466e38f)
#define IDX_INF 0x7fffffff

__device__ __forceinline__ ushort f2bf(float x) {
  uint u = __float_as_uint(x);
  u = u + 0x7fffu + ((u >> 16) & 1u);   // RNE
  return (ushort)(u >> 16);
}

// Strict total order: larger value wins; ties -> smaller index wins.
#define BETTER(av, ai, bv, bi) ((av) > (bv) || ((av) == (bv) && (ai) < (bi)))

// ---------------------------------------------------------------------------
__global__ __launch_bounds__(256) void k_setup(const float* __restrict__ enc,
                                               const float* __restrict__ emb,
                                               float* __restrict__ flatT,
                                               float* __restrict__ xT,
                                               int* __restrict__ fin0) {
  int idx = blockIdx.x * 256 + threadIdx.x;   // 65536
  int j = idx >> 6, b = idx & 63;
  float v = (j < 512) ? enc[b * 512 + j] : enc[32768 + b * 512 + (j - 512)];
  flatT[j * 64 + b] = v;
  if (j < 512) xT[j * 64 + b] = emb[SOS_TOK * EE + j];
  if (idx < 64) fin0[idx] = 0;
}

// ---------------------------------------------------------------------------
// Optional: pack out_w fp32 -> bf16 in B-fragment stream order.
// chunk c = (nt*32 + kc)*64 + lane ; element j: n = nt*16+(lane&15), k = kc*32+(lane>>4)*8+j
__global__ __launch_bounds__(256) void k_packWb(const float* __restrict__ W,
                                                ushort* __restrict__ Wb) {
  int t = blockIdx.x * 256 + threadIdx.x;     // 4,096,000 chunks
  int l = t & 63, kc = (t >> 6) & 31, nt = t >> 11;
  int n = nt * 16 + (l & 15);
  int k = kc * 32 + ((l >> 4) << 3);
  const float* src = W + (size_t)n * 1024 + k;
  ushort8 r;
  #pragma unroll
  for (int j = 0; j < 8; ++j) r[j] = f2bf(src[j]);
  *(ushort8*)(Wb + (size_t)t * 8) = r;
}

// ---------------------------------------------------------------------------
// Generic fp32 skinny GEMM partial (setup only).
__global__ __launch_bounds__(256) void k_gemm(const float* __restrict__ AT,
                                              const float* __restrict__ W,
                                              int ldw, int wofs,
                                              float* __restrict__ C, int N) {
  __shared__ float Ws[KSEG][65];
  int tid = threadIdx.x;
  int n0 = blockIdx.x * 64;
  int k0 = blockIdx.y * KSEG;

  #pragma unroll
  for (int r = 0; r < 8; ++r) {
    int f4 = tid + 256 * r;
    int n = f4 >> 5, kq = f4 & 31;
    float4 w4 = *(const float4*)&W[(size_t)(n0 + n) * ldw + wofs + k0 + 4 * kq];
    Ws[4 * kq + 0][n] = w4.x;
    Ws[4 * kq + 1][n] = w4.y;
    Ws[4 * kq + 2][n] = w4.z;
    Ws[4 * kq + 3][n] = w4.w;
  }
  __syncthreads();

  int wv = __builtin_amdgcn_readfirstlane(tid >> 6);
  int lane = tid & 63;
  int mb = wv * 16;

  float acc[16];
  #pragma unroll
  for (int i = 0; i < 16; ++i) acc[i] = 0.f;

  #pragma unroll 4
  for (int kk = 0; kk < KSEG; ++kk) {
    float w = Ws[kk][lane];
    const float* a = &AT[(size_t)(k0 + kk) * 64 + mb];
    float av[16];
    *(float4*)&av[0]  = *(const float4*)(a + 0);
    *(float4*)&av[4]  = *(const float4*)(a + 4);
    *(float4*)&av[8]  = *(const float4*)(a + 8);
    *(float4*)&av[12] = *(const float4*)(a + 12);
    #pragma unroll
    for (int i = 0; i < 16; ++i) acc[i] += av[i] * w;
  }

  float* dst = C + ((size_t)blockIdx.y * 64 + mb) * N + n0 + lane;
  #pragma unroll
  for (int i = 0; i < 16; ++i) dst[(size_t)i * N] = acc[i];
}

// ---------------------------------------------------------------------------
// Per-step gates GEMM with base_by selector.
// by_eff < 4  -> gi seg (xT @ W_ih[:, :512]), K-seg 128 each, P slot = by_eff
// by_eff >= 4 -> gh (hT @ W_hh), 256 K each (two 128 stages), P slot = by_eff
__global__ __launch_bounds__(256) void k_gates(const float* __restrict__ xT,
                                               const float* __restrict__ hT,
                                               const float* __restrict__ Wih,
                                               const float* __restrict__ Whh,
                                               float* __restrict__ P,
                                               int base_by) {
  __shared__ float Ws[KSEG][65];
  int tid = threadIdx.x;
  int n0 = blockIdx.x * 64;
  int by = blockIdx.y + base_by;
  bool gi = (by < 4);
  const float* AT = gi ? xT : hT;
  const float* W  = gi ? Wih : Whh;
  int ldw = gi ? 1536 : 1024;
  int nsegs = gi ? 1 : 2;
  int k0base = gi ? by * KSEG : (by - 4) * 256;

  int wv = __builtin_amdgcn_readfirstlane(tid >> 6);
  int lane = tid & 63;
  int mb = wv * 16;

  float acc[16];
  #pragma unroll
  for (int i = 0; i < 16; ++i) acc[i] = 0.f;

  for (int s = 0; s < nsegs; ++s) {
    int k0 = k0base + s * KSEG;
    if (s) __syncthreads();
    #pragma unroll
    for (int r = 0; r < 8; ++r) {
      int f4 = tid + 256 * r;
      int n = f4 >> 5, kq = f4 & 31;
      float4 w4 = *(const float4*)&W[(size_t)(n0 + n) * ldw + k0 + 4 * kq];
      Ws[4 * kq + 0][n] = w4.x;
      Ws[4 * kq + 1][n] = w4.y;
      Ws[4 * kq + 2][n] = w4.z;
      Ws[4 * kq + 3][n] = w4.w;
    }
    __syncthreads();
    #pragma unroll 4
    for (int kk = 0; kk < KSEG; ++kk) {
      float w = Ws[kk][lane];
      const float* a = &AT[(size_t)(k0 + kk) * 64 + mb];
      float av[16];
      *(float4*)&av[0]  = *(const float4*)(a + 0);
      *(float4*)&av[4]  = *(const float4*)(a + 4);
      *(float4*)&av[8]  = *(const float4*)(a + 8);
      *(float4*)&av[12] = *(const float4*)(a + 12);
      #pragma unroll
      for (int i = 0; i < 16; ++i) acc[i] += av[i] * w;
    }
  }

  float* dst = P + ((size_t)by * 64 + mb) * G3 + n0 + lane;
  #pragma unroll
  for (int i = 0; i < 16; ++i) dst[(size_t)i * G3] = acc[i];
}

// ---------------------------------------------------------------------------
__global__ __launch_bounds__(256) void k_reduce_gc(const float* __restrict__ P,
                                                   const float* __restrict__ b_ih,
                                                   float* __restrict__ gc) {
  int idx = blockIdx.x * 256 + threadIdx.x;  // 196608
  int n = idx % G3;
  float s = b_ih[n];
  #pragma unroll
  for (int p = 0; p < 8; ++p) s += P[(size_t)p * (64 * G3) + idx];
  gc[idx] = s;
}

// Pack one h element (m=b, k=g) into bf16 A-frag layout.
__device__ __forceinline__ void packH1(float v, int b, int g, ushort* hA) {
  int kc = g >> 5, q = (g >> 3) & 3, j = g & 7;
  int lane = (q << 4) | (b & 15), mt = b >> 4;
  size_t fi = ((size_t)((mt * 32 + kc) * 64 + lane)) * 8 + j;
  hA[fi] = f2bf(v);
}

__global__ __launch_bounds__(256) void k_reduce_h0(const float* __restrict__ Ph,
                                                   const float* __restrict__ Wh_b,
                                                   float* __restrict__ hT,
                                                   float* __restrict__ hB,
                                                   ushort* __restrict__ hA) {
  int idx = blockIdx.x * 256 + threadIdx.x;  // 65536
  int b = idx >> 10, g = idx & 1023;
  float s = Wh_b[g];
  #pragma unroll
  for (int p = 0; p < 8; ++p) s += Ph[(size_t)p * 65536 + idx];
  hT[g * 64 + b] = s;
  hB[idx] = s;                 // hB[b][g]
  packH1(s, b, g, hA);
}

// ---------------------------------------------------------------------------
// GRU combine; emits fp32 hT (g-major), hB (b-major) and bf16 A-frag hA.
// P slots 0..3 gi, 4..7 gh. 256 blocks: b = bx>>2, g-range (bx&3)*256+tid.
__global__ __launch_bounds__(256) void k_combine(const float* __restrict__ P,
                                                 const float* __restrict__ gc,
                                                 const float* __restrict__ b_hh,
                                                 float* __restrict__ hT,
                                                 float* __restrict__ hB,
                                                 ushort* __restrict__ hA) {
  int b = blockIdx.x >> 2;
  int g = ((blockIdx.x & 3) << 8) + threadIdx.x;
  float ir = gc[b * G3 + g];
  float iz = gc[b * G3 + 1024 + g];
  float in_ = gc[b * G3 + 2048 + g];
  float hr = b_hh[g], hz = b_hh[1024 + g], hn = b_hh[2048 + g];
  #pragma unroll
  for (int p = 0; p < 4; ++p) {
    const float* row = P + ((size_t)p * 64 + b) * G3;
    ir += row[g]; iz += row[1024 + g]; in_ += row[2048 + g];
  }
  #pragma unroll
  for (int p = 4; p < 8; ++p) {
    const float* row = P + ((size_t)p * 64 + b) * G3;
    hr += row[g]; hz += row[1024 + g]; hn += row[2048 + g];
  }
  float rr = 1.f / (1.f + expf(-(ir + hr)));
  float zz = 1.f / (1.f + expf(-(iz + hz)));
  float nn = tanhf(in_ + rr * hn);
  float hold = hT[g * 64 + b];
  float hnew = (1.f - zz) * nn + zz * hold;
  hT[g * 64 + b] = hnew;
  hB[b * 1024 + g] = hnew;
  packH1(hnew, b, g, hA);
}

// ---------------------------------------------------------------------------
__device__ __forceinline__ short8 cvt8(const float* p) {
  float4 x = *(const float4*)p;
  float4 y = *(const float4*)(p + 4);
  short8 r;
  r[0] = (short)f2bf(x.x); r[1] = (short)f2bf(x.y);
  r[2] = (short)f2bf(x.z); r[3] = (short)f2bf(x.w);
  r[4] = (short)f2bf(y.x); r[5] = (short)f2bf(y.y);
  r[6] = (short)f2bf(y.z); r[7] = (short)f2bf(y.w);
  return r;
}

// MFMA logits + fused next-step gh gates.
// Blocks 0..GHB-1: gh GEMM for step t+1 (hT(t+1) @ W_hh -> P slots 4..7).
// Blocks GHB..GHB+LOGB-1: logits, wave = 1 n-tile (16 vocab) x 4 m-tiles,
// depth-4 ring; per-wave top-2 partials written b-major for coalesced k_finish.
template <bool PACKED>
__global__ __launch_bounds__(256) void k_logits(const ushort* __restrict__ Wb,
                                                const float* __restrict__ Wf,
                                                const ushort* __restrict__ hA,
                                                const float* __restrict__ bo,
                                                float* __restrict__ pmax,
                                                int* __restrict__ pidx,
                                                const float* __restrict__ hT,
                                                const float* __restrict__ Whh,
                                                float* __restrict__ P) {
  __shared__ float Ws[KSEG][65];
  int tid = threadIdx.x, wv = tid >> 6, lane = tid & 63;

  if (blockIdx.x < GHB) {
    // ---- gh path: hT @ W_hh^T into P slots 4..7 (for NEXT step's combine) ----
    int bx = blockIdx.x;
    int by = bx / 48;               // 0..3
    int n0 = (bx % 48) * 64;
    int slot = 4 + by;
    int k0base = by * 256;

    int wvs = __builtin_amdgcn_readfirstlane(wv);
    int mb = wvs * 16;

    float acc[16];
    #pragma unroll
    for (int i = 0; i < 16; ++i) acc[i] = 0.f;

    for (int s = 0; s < 2; ++s) {
      int k0 = k0base + s * KSEG;
      if (s) __syncthreads();
      #pragma unroll
      for (int r = 0; r < 8; ++r) {
        int f4 = tid + 256 * r;
        int n = f4 >> 5, kq = f4 & 31;
        float4 w4 = *(const float4*)&Whh[(size_t)(n0 + n) * 1024 + k0 + 4 * kq];
        Ws[4 * kq + 0][n] = w4.x;
        Ws[4 * kq + 1][n] = w4.y;
        Ws[4 * kq + 2][n] = w4.z;
        Ws[4 * kq + 3][n] = w4.w;
      }
      __syncthreads();
      #pragma unroll 4
      for (int kk = 0; kk < KSEG; ++kk) {
        float w = Ws[kk][lane];
        const float* a = &hT[(size_t)(k0 + kk) * 64 + mb];
        float av[16];
        *(float4*)&av[0]  = *(const float4*)(a + 0);
        *(float4*)&av[4]  = *(const float4*)(a + 4);
        *(float4*)&av[8]  = *(const float4*)(a + 8);
        *(float4*)&av[12] = *(const float4*)(a + 12);
        #pragma unroll
        for (int i = 0; i < 16; ++i) acc[i] += av[i] * w;
      }
    }

    float* dst = P + ((size_t)slot * 64 + mb) * G3 + n0 + lane;
    #pragma unroll
    for (int i = 0; i < 16; ++i) dst[(size_t)i * G3] = acc[i];
    return;
  }

  // ---- logits path ----
  int nt = (blockIdx.x - GHB) * 4 + wv;   // 0..1999
  int nl = lane & 15, q = lane >> 4;

  const short8* Bp = (const short8*)Wb + ((size_t)nt * 2048 + lane);
  const float*  Bf = Wf + (size_t)(nt * 16 + nl) * 1024 + (q << 3);
  const short8* Ap = (const short8*)hA + lane;

  f32x4 acc[4];
  #pragma unroll
  for (int m = 0; m < 4; ++m) acc[m] = (f32x4){0.f, 0.f, 0.f, 0.f};

  short8 bR[4], aR[4][4];
  #pragma unroll
  for (int d = 0; d < 4; ++d) {
    bR[d] = PACKED ? Bp[d * 64] : cvt8(Bf + d * 32);
    #pragma unroll
    for (int m = 0; m < 4; ++m) aR[d][m] = Ap[(m * 32 + d) * 64];
  }

  #pragma unroll
  for (int kc = 0; kc < 32; ++kc) {
    const int sl = kc & 3;
    #pragma unroll
    for (int m = 0; m < 4; ++m)
      acc[m] = __builtin_amdgcn_mfma_f32_16x16x32_bf16(aR[sl][m], bR[sl], acc[m], 0, 0, 0);
    if (kc < 28) {
      bR[sl] = PACKED ? Bp[(kc + 4) * 64] : cvt8(Bf + (kc + 4) * 32);
      #pragma unroll
      for (int m = 0; m < 4; ++m) aR[sl][m] = Ap[(m * 32 + kc + 4) * 64];
    }
  }

  // Epilogue: bias + per-row top-2 over this wave's 16 columns, b-major out.
  float bias = bo[nt * 16 + nl];
  int myn = nt * 16 + nl;
  #pragma unroll
  for (int mt = 0; mt < 4; ++mt) {
    #pragma unroll
    for (int r = 0; r < 4; ++r) {
      float v1 = acc[mt][r] + bias; int i1 = myn;
      float v2 = NEG_INF;           int i2 = IDX_INF;
      #pragma unroll
      for (int s = 1; s < 16; s <<= 1) {
        float ov1 = __shfl_xor(v1, s, 64); int oi1 = __shfl_xor(i1, s, 64);
        float ov2 = __shfl_xor(v2, s, 64); int oi2 = __shfl_xor(i2, s, 64);
        bool take = BETTER(ov1, oi1, v1, i1);
        float n1v = take ? ov1 : v1; int n1i = take ? oi1 : i1;
        float cav = take ? v1 : ov1; int cai = take ? i1 : oi1;
        float cbv = take ? ov2 : v2; int cbi = take ? oi2 : i2;
        bool bb = BETTER(cbv, cbi, cav, cai);
        v1 = n1v; i1 = n1i;
        v2 = bb ? cbv : cav; i2 = bb ? cbi : cai;
      }
      if (nl == 0) {
        int m = mt * 16 + q * 4 + r;
        pmax[(size_t)m * NP2 + nt * 2 + 0] = v1;
        pidx[(size_t)m * NP2 + nt * 2 + 0] = i1;
        pmax[(size_t)m * NP2 + nt * 2 + 1] = v2;
        pidx[(size_t)m * NP2 + nt * 2 + 1] = i2;
      }
    }
  }
}

// ---------------------------------------------------------------------------
// Per-batch finisher: low-barrier top-4 selection -> fp64 rescore -> token,
// fin, embedding gather. One block per batch.
// Selection: per-thread sorted top-4 (16 contiguous candidates, all indices
// distinct within a batch) -> 6-level shfl_xor bitonic merge (no barriers)
// -> one LDS merge of 4 wave results (1 barrier).
__global__ __launch_bounds__(256) void k_finish(const float* __restrict__ pmax,
                                                const int* __restrict__ pidx,
                                                const float* __restrict__ hB,
                                                const float* __restrict__ Wf,
                                                const float* __restrict__ bo,
                                                const float* __restrict__ emb,
                                                const int* __restrict__ fin_old,
                                                int* __restrict__ fin_new,
                                                float* __restrict__ xT,
                                                float* __restrict__ tok_out, int t) {
  __shared__ float  sv[16];
  __shared__ int    si[16];
  __shared__ int    sch[4];
  __shared__ double ssc[4];
  __shared__ int    sinp;
  int b = blockIdx.x, tid = threadIdx.x;
  int wv = tid >> 6, ln = tid & 63;

  float v0 = NEG_INF, v1 = NEG_INF, v2 = NEG_INF, v3 = NEG_INF;
  int   i0 = IDX_INF, i1 = IDX_INF, i2 = IDX_INF, i3 = IDX_INF;

  // Insert (cv,ci) into the descending sorted top-4 (v0..v3).
  #define INS4(cv, ci)                                                   \
    {                                                                    \
      bool c0 = BETTER(cv, ci, v0, i0);                                  \
      bool c1 = BETTER(cv, ci, v1, i1);                                  \
      bool c2 = BETTER(cv, ci, v2, i2);                                  \
      bool c3 = BETTER(cv, ci, v3, i3);                                  \
      v3 = c3 ? (c2 ? v2 : (cv)) : v3;  i3 = c3 ? (c2 ? i2 : (ci)) : i3; \
      v2 = c2 ? (c1 ? v1 : (cv)) : v2;  i2 = c2 ? (c1 ? i1 : (ci)) : i2; \
      v1 = c1 ? (c0 ? v0 : (cv)) : v1;  i1 = c1 ? (c0 ? i0 : (ci)) : i1; \
      v0 = c0 ? (cv) : v0;              i0 = c0 ? (ci) : i0;             \
    }

  if (tid < 250) {                       // 250*16 == NP2
    const float* pm = pmax + (size_t)b * NP2 + tid * 16;
    const int*   pi = pidx + (size_t)b * NP2 + tid * 16;
    #pragma unroll
    for (int j4 = 0; j4 < 4; ++j4) {
      float4 c4 = *(const float4*)(pm + j4 * 4);
      int4   x4 = *(const int4*)(pi + j4 * 4);
      INS4(c4.x, x4.x);
      INS4(c4.y, x4.y);
      INS4(c4.z, x4.z);
      INS4(c4.w, x4.w);
    }
  }

  // Compare-exchange keeping the better at (xv,xi).
  #define CESW(xv, xi, yv, yi)                                     \
    {                                                              \
      bool sw_ = BETTER(yv, yi, xv, xi);                           \
      float tv_ = xv; int ti_ = xi;                                \
      xv = sw_ ? yv : xv;  xi = sw_ ? yi : xi;                     \
      yv = sw_ ? tv_ : yv; yi = sw_ ? ti_ : yi;                    \
    }

  // Wave-level butterfly merge of sorted top-4 lists (no barriers).
  for (int s = 1; s < 64; s <<= 1) {
    float w0 = __shfl_xor(v0, s, 64), w1 = __shfl_xor(v1, s, 64);
    float w2 = __shfl_xor(v2, s, 64), w3 = __shfl_xor(v3, s, 64);
    int   j0 = __shfl_xor(i0, s, 64), j1 = __shfl_xor(i1, s, 64);
    int   j2 = __shfl_xor(i2, s, 64), j3 = __shfl_xor(i3, s, 64);
    // bitonic 8-seq: [v0 v1 v2 v3 w3 w2 w1 w0]; half-clean keeps max in v.
    if (BETTER(w3, j3, v0, i0)) { v0 = w3; i0 = j3; }
    if (BETTER(w2, j2, v1, i1)) { v1 = w2; i1 = j2; }
    if (BETTER(w1, j1, v2, i2)) { v2 = w1; i2 = j1; }
    if (BETTER(w0, j0, v3, i3)) { v3 = w0; i3 = j0; }
    // sort the remaining bitonic 4 descending.
    CESW(v0, i0, v2, i2);
    CESW(v1, i1, v3, i3);
    CESW(v0, i0, v1, i1);
    CESW(v2, i2, v3, i3);
  }

  if (ln == 0) {
    sv[wv * 4 + 0] = v0; si[wv * 4 + 0] = i0;
    sv[wv * 4 + 1] = v1; si[wv * 4 + 1] = i1;
    sv[wv * 4 + 2] = v2; si[wv * 4 + 2] = i2;
    sv[wv * 4 + 3] = v3; si[wv * 4 + 3] = i3;
  }
  __syncthreads();

  if (tid == 0) {
    float t0 = NEG_INF, t1 = NEG_INF, t2 = NEG_INF, t3 = NEG_INF;
    int   x0 = IDX_INF, x1 = IDX_INF, x2 = IDX_INF, x3 = IDX_INF;
    #pragma unroll
    for (int e = 0; e < 16; ++e) {
      float cv = sv[e]; int ci = si[e];
      bool c0 = BETTER(cv, ci, t0, x0);
      bool c1 = BETTER(cv, ci, t1, x1);
      bool c2 = BETTER(cv, ci, t2, x2);
      bool c3 = BETTER(cv, ci, t3, x3);
      t3 = c3 ? (c2 ? t2 : cv) : t3;  x3 = c3 ? (c2 ? x2 : ci) : x3;
      t2 = c2 ? (c1 ? t1 : cv) : t2;  x2 = c2 ? (c1 ? x1 : ci) : x2;
      t1 = c1 ? (c0 ? t0 : cv) : t1;  x1 = c1 ? (c0 ? x0 : ci) : x1;
      t0 = c0 ? cv : t0;              x0 = c0 ? ci : x0;
    }
    sch[0] = x0; sch[1] = x1; sch[2] = x2; sch[3] = x3;
  }
  __syncthreads();

  // fp64 rescore: wave c handles candidate c; hB/Wf streamed as float4.
  int c = wv;
  int cid = sch[c];
  const float4* hv4 = (const float4*)(hB + (size_t)b * 1024);
  const float4* wv4 = (const float4*)(Wf + (size_t)cid * 1024);
  double s = 0.0;
  #pragma unroll
  for (int j = 0; j < 4; ++j) {
    float4 hx = hv4[j * 64 + ln];
    float4 wx = wv4[j * 64 + ln];
    s += (double)hx.x * (double)wx.x + (double)hx.y * (double)wx.y +
         (double)hx.z * (double)wx.z + (double)hx.w * (double)wx.w;
  }
  #pragma unroll
  for (int sh = 1; sh < 64; sh <<= 1) s += __shfl_xor(s, sh, 64);
  if (ln == 0) ssc[c] = s + (double)bo[cid];
  __syncthreads();

  if (tid == 0) {
    double bs = ssc[0]; int bid = sch[0];
    #pragma unroll
    for (int j = 1; j < 4; ++j)
      if (ssc[j] > bs || (ssc[j] == bs && sch[j] < bid)) { bs = ssc[j]; bid = sch[j]; }
    int tok = bid;
    int f = fin_old[b] | (tok == EOS_TOK ? 1 : 0);
    tok_out[b * TT + t] = (float)tok;
    fin_new[b] = f;
    sinp = f ? EOS_TOK : tok;
  }
  __syncthreads();
  int inp = sinp;
  xT[tid * 64 + b]         = emb[(size_t)inp * EE + tid];
  xT[(tid + 256) * 64 + b] = emb[(size_t)inp * EE + tid + 256];
}

// ---------------------------------------------------------------------------
__global__ __launch_bounds__(256) void k_hout(const float* __restrict__ hB,
                                              float* __restrict__ outH) {
  int idx = blockIdx.x * 256 + threadIdx.x;  // 65536
  outH[idx] = hB[idx];   // hB is already [b][g] = output layout
}

// ---------------------------------------------------------------------------
extern "C" void kernel_launch(void* const* d_in, const int* in_sizes, int n_in,
                              void* d_out, int out_size, void* d_ws, size_t ws_size,
                              hipStream_t stream) {
  const float* enc   = (const float*)d_in[0];
  const float* emb   = (const float*)d_in[1];
  const float* Wh_w  = (const float*)d_in[2];
  const float* Wh_b  = (const float*)d_in[3];
  const float* W_ih  = (const float*)d_in[4];
  const float* W_hh  = (const float*)d_in[5];
  const float* b_ih  = (const float*)d_in[6];
  const float* b_hh  = (const float*)d_in[7];
  const float* out_w = (const float*)d_in[8];
  const float* out_b = (const float*)d_in[9];

  float* ws    = (float*)d_ws;
  float* flatT = ws + OFF_FLATT;
  float* xT    = ws + OFF_XT;
  float* hT    = ws + OFF_HT;
  float* gc    = ws + OFF_GC;
  float* P     = ws + OFF_P;
  float* Ph    = ws + OFF_PH;
  float* pmax  = ws + OFF_PMAX;
  int*   pidx  = (int*)(ws + OFF_PIDX);
  int*   fin   = (int*)(ws + OFF_FIN);
  ushort* hA   = (ushort*)(ws + OFF_HA);
  float* hB    = ws + OFF_HB;
  ushort* Wb   = (ushort*)(ws + OFF_WB);

  float* outTok = (float*)d_out;
  float* outH   = (float*)d_out + BB * TT;

  const bool packed = (ws_size >= NEED_BYTES);

  // Setup
  k_setup<<<256, 256, 0, stream>>>(enc, emb, flatT, xT, fin);
  if (packed) k_packWb<<<16000, 256, 0, stream>>>(out_w, Wb);
  // gc = b_ih + context @ W_ih[:, 512:1536]^T
  k_gemm<<<dim3(48, 8), 256, 0, stream>>>(flatT, W_ih, 1536, 512, P, G3);
  k_reduce_gc<<<768, 256, 0, stream>>>(P, b_ih, gc);
  // h0 = flat @ Wh_w^T + Wh_b
  k_gemm<<<dim3(16, 8), 256, 0, stream>>>(flatT, Wh_w, 1024, 0, Ph, HH);
  k_reduce_h0<<<256, 256, 0, stream>>>(Ph, Wh_b, hT, hB, hA);
  // gh for t=0 (P slots 4..7); later steps get gh fused into k_logits.
  k_gates<<<dim3(48, 4), 256, 0, stream>>>(xT, hT, W_ih, W_hh, P, 4);

  for (int t = 0; t < TT; ++t) {
    // gi only (P slots 0..3); gh for step t was computed by k_logits(t-1)/setup.
    k_gates<<<dim3(48, 4), 256, 0, stream>>>(xT, hT, W_ih, W_hh, P, 0);
    k_combine<<<256, 256, 0, stream>>>(P, gc, b_hh, hT, hB, hA);
    if (packed)
      k_logits<true><<<LOGB + GHB, 256, 0, stream>>>(Wb, out_w, hA, out_b, pmax, pidx,
                                                     hT, W_hh, P);
    else
      k_logits<false><<<LOGB + GHB, 256, 0, stream>>>(Wb, out_w, hA, out_b, pmax, pidx,
                                                      hT, W_hh, P);
    k_finish<<<64, 256, 0, stream>>>(pmax, pidx, hB, out_w, out_b, emb,
                                     fin + (t & 1) * 64, fin + ((t + 1) & 1) * 64,
                                     xT, outTok, t);
  }
  k_hout<<<256, 256, 0, stream>>>(hB, outH);
}